// Round 1
// baseline (1389.090 us; speedup 1.0000x reference)
//
#include <hip/hip_runtime.h>
#include <hip/hip_bf16.h>
#include <math.h>

// Problem constants (fixed by reference)
#define D_MODEL   768
#define D_STATE   16
#define D_CONV    4
#define D_INNER   1536
#define DT_RANK   48
#define BATCH     4
#define SEQ_LEN   2048
#define BL        (BATCH * SEQ_LEN)        // 8192 rows
#define NCHUNK    32
#define CHUNK     (SEQ_LEN / NCHUNK)       // 64

// ---------------------------------------------------------------------------
// Tiled fp32 SGEMM, C[m,n] = sum_k A[m,k] * B[n,k]  (both row-major, "NT")
// BM=BN=128, BK=8, 256 threads, 8x8 per-thread microtile.
// MODE 0: plain store.  MODE 1: v = softplus(v + bias[n]) (for dt).
// M must be a multiple of 128; N guarded; K must be a multiple of 8.
// ---------------------------------------------------------------------------
template <int MODE>
__global__ __launch_bounds__(256)
void sgemm_nt(const float* __restrict__ A, const float* __restrict__ B,
              float* __restrict__ C, const float* __restrict__ bias,
              int M, int N, int K, int lda, int ldb, int ldc)
{
    const int BM = 128, BN = 128, BK = 8;
    __shared__ float As[BK][BM];
    __shared__ float Bs[BK][BN];

    const int tid  = threadIdx.x;
    const int bm   = blockIdx.y * BM;
    const int bn   = blockIdx.x * BN;
    const int lrow = tid >> 1;            // 0..127
    const int lk   = (tid & 1) * 4;       // 0 or 4

    const float* Aload = A + (long)(bm + lrow) * lda + lk;
    const float* Bload = B + (long)(bn + lrow) * ldb + lk;
    const bool bvalid = (bn + lrow) < N;

    const int tx = tid & 15;              // col group
    const int ty = tid >> 4;              // row group

    float acc[8][8];
    #pragma unroll
    for (int i = 0; i < 8; ++i)
        #pragma unroll
        for (int j = 0; j < 8; ++j) acc[i][j] = 0.f;

    for (int k0 = 0; k0 < K; k0 += BK) {
        float4 av = *(const float4*)(Aload + k0);
        float4 bv = bvalid ? *(const float4*)(Bload + k0)
                           : make_float4(0.f, 0.f, 0.f, 0.f);
        __syncthreads();   // previous iter's LDS reads done
        As[lk + 0][lrow] = av.x; As[lk + 1][lrow] = av.y;
        As[lk + 2][lrow] = av.z; As[lk + 3][lrow] = av.w;
        Bs[lk + 0][lrow] = bv.x; Bs[lk + 1][lrow] = bv.y;
        Bs[lk + 2][lrow] = bv.z; Bs[lk + 3][lrow] = bv.w;
        __syncthreads();

        #pragma unroll
        for (int k = 0; k < BK; ++k) {
            float4 a0 = *(const float4*)&As[k][ty * 8];
            float4 a1 = *(const float4*)&As[k][ty * 8 + 4];
            float4 b0 = *(const float4*)&Bs[k][tx * 8];
            float4 b1 = *(const float4*)&Bs[k][tx * 8 + 4];
            float a[8] = {a0.x, a0.y, a0.z, a0.w, a1.x, a1.y, a1.z, a1.w};
            float b[8] = {b0.x, b0.y, b0.z, b0.w, b1.x, b1.y, b1.z, b1.w};
            #pragma unroll
            for (int i = 0; i < 8; ++i)
                #pragma unroll
                for (int j = 0; j < 8; ++j)
                    acc[i][j] = fmaf(a[i], b[j], acc[i][j]);
        }
    }

    #pragma unroll
    for (int i = 0; i < 8; ++i) {
        const int row = bm + ty * 8 + i;
        #pragma unroll
        for (int j = 0; j < 8; ++j) {
            const int col = bn + tx * 8 + j;
            if (col < N) {
                float v = acc[i][j];
                if (MODE == 1) {
                    v += bias[col];
                    v = fmaxf(v, 0.f) + log1pf(__expf(-fabsf(v)));  // stable softplus
                }
                C[(long)row * ldc + col] = v;
            }
        }
    }
}

// ---------------------------------------------------------------------------
// Depthwise causal conv (width 4) + bias + SiLU.
// ---------------------------------------------------------------------------
__global__ __launch_bounds__(256)
void conv_silu_kernel(const float* __restrict__ xz,
                      const float* __restrict__ conv_w,
                      const float* __restrict__ conv_b,
                      float* __restrict__ xc)
{
    const long idx = (long)blockIdx.x * 256 + threadIdx.x;  // over BL*D_INNER
    const int d  = (int)(idx % D_INNER);
    const long bl = idx / D_INNER;
    const int l  = (int)(bl % SEQ_LEN);

    const float w0 = conv_w[d * 4 + 0];
    const float w1 = conv_w[d * 4 + 1];
    const float w2 = conv_w[d * 4 + 2];
    const float w3 = conv_w[d * 4 + 3];

    const float* base = xz + bl * 3072 + d;
    float s = conv_b[d];
    if (l >= 3) s = fmaf(base[-3 * 3072], w0, s);
    if (l >= 2) s = fmaf(base[-2 * 3072], w1, s);
    if (l >= 1) s = fmaf(base[-1 * 3072], w2, s);
    s = fmaf(base[0], w3, s);
    const float sig = 1.f / (1.f + __expf(-s));
    xc[bl * D_INNER + d] = s * sig;
}

// ---------------------------------------------------------------------------
// Scan phase A: per (b, d, chunk) compute P = prod(a_l), S = local scan (h0=0)
// Layout of P/S/H: idx = ((b*NCHUNK + c)*16 + n)*D_INNER + d
// dt lives in xz cols 0..1535; B/C in xdbl cols 48..79.
// ---------------------------------------------------------------------------
__global__ __launch_bounds__(256)
void scan_phaseA(const float* __restrict__ xc, const float* __restrict__ xz,
                 const float* __restrict__ xdbl, const float* __restrict__ A_log,
                 float* __restrict__ P, float* __restrict__ S)
{
    const int d = blockIdx.x * 256 + threadIdx.x;
    const int c = blockIdx.y;
    const int b = blockIdx.z;

    float An[16], Pr[16], Sr[16];
    #pragma unroll
    for (int n = 0; n < 16; ++n) {
        An[n] = -__expf(A_log[d * 16 + n]);
        Pr[n] = 1.f;
        Sr[n] = 0.f;
    }

    const long bl0 = (long)b * SEQ_LEN + (long)c * CHUNK;
    for (int l = 0; l < CHUNK; ++l) {
        const long bl = bl0 + l;
        const float dt  = xz[bl * 3072 + d];
        const float x   = xc[bl * D_INNER + d];
        const float dtx = dt * x;
        const float* bc = xdbl + bl * 80 + DT_RANK;   // B_t[0..15]
        #pragma unroll
        for (int n = 0; n < 16; ++n) {
            const float a = __expf(dt * An[n]);
            Pr[n] *= a;
            Sr[n] = fmaf(a, Sr[n], dtx * bc[n]);
        }
    }

    const long base = ((long)(b * NCHUNK + c) * 16) * D_INNER + d;
    #pragma unroll
    for (int n = 0; n < 16; ++n) {
        P[base + (long)n * D_INNER] = Pr[n];
        S[base + (long)n * D_INNER] = Sr[n];
    }
}

// ---------------------------------------------------------------------------
// Scan phase B: sequential chunk-combine per (b, d): H[c] = h_in for chunk c.
// ---------------------------------------------------------------------------
__global__ __launch_bounds__(256)
void scan_phaseB(const float* __restrict__ P, const float* __restrict__ S,
                 float* __restrict__ H)
{
    const int t = blockIdx.x * 256 + threadIdx.x;   // over BATCH*D_INNER
    const int d = t % D_INNER;
    const int b = t / D_INNER;

    float h[16];
    #pragma unroll
    for (int n = 0; n < 16; ++n) h[n] = 0.f;

    for (int c = 0; c < NCHUNK; ++c) {
        const long base = ((long)(b * NCHUNK + c) * 16) * D_INNER + d;
        #pragma unroll
        for (int n = 0; n < 16; ++n) {
            const long i = base + (long)n * D_INNER;
            H[i] = h[n];
            h[n] = fmaf(P[i], h[n], S[i]);
        }
    }
}

// ---------------------------------------------------------------------------
// Scan phase C: re-run chunks from correct h_in, emit y, gate with silu(z),
// write y over xc in place (each location read+written by its own thread).
// ---------------------------------------------------------------------------
__global__ __launch_bounds__(256)
void scan_phaseC(float* xc, const float* __restrict__ xz,
                 const float* __restrict__ xdbl, const float* __restrict__ A_log,
                 const float* __restrict__ Dp, const float* __restrict__ H)
{
    const int d = blockIdx.x * 256 + threadIdx.x;
    const int c = blockIdx.y;
    const int b = blockIdx.z;

    float An[16], h[16];
    const long hbase = ((long)(b * NCHUNK + c) * 16) * D_INNER + d;
    #pragma unroll
    for (int n = 0; n < 16; ++n) {
        An[n] = -__expf(A_log[d * 16 + n]);
        h[n]  = H[hbase + (long)n * D_INNER];
    }
    const float Dd = Dp[d];

    const long bl0 = (long)b * SEQ_LEN + (long)c * CHUNK;
    for (int l = 0; l < CHUNK; ++l) {
        const long bl = bl0 + l;
        const float dt  = xz[bl * 3072 + d];
        const float x   = xc[bl * D_INNER + d];
        const float dtx = dt * x;
        const float* bc = xdbl + bl * 80 + DT_RANK;  // B_t then C_t
        float y = Dd * x;
        #pragma unroll
        for (int n = 0; n < 16; ++n) {
            const float a = __expf(dt * An[n]);
            h[n] = fmaf(a, h[n], dtx * bc[n]);
            y = fmaf(h[n], bc[16 + n], y);
        }
        const float z  = xz[bl * 3072 + D_INNER + d];
        const float sz = z / (1.f + __expf(-z));
        xc[bl * D_INNER + d] = y * sz;
    }
}

// ---------------------------------------------------------------------------
extern "C" void kernel_launch(void* const* d_in, const int* in_sizes, int n_in,
                              void* d_out, int out_size, void* d_ws, size_t ws_size,
                              hipStream_t stream)
{
    const float* x      = (const float*)d_in[0];   // (4,2048,768)
    const float* W_in   = (const float*)d_in[1];   // (3072,768)
    const float* conv_w = (const float*)d_in[2];   // (1536,1,4)
    const float* conv_b = (const float*)d_in[3];   // (1536,)
    const float* W_x    = (const float*)d_in[4];   // (80,1536)
    const float* W_dt   = (const float*)d_in[5];   // (1536,48)
    const float* b_dt   = (const float*)d_in[6];   // (1536,)
    const float* A_log  = (const float*)d_in[7];   // (1536,16)
    const float* D_p    = (const float*)d_in[8];   // (1536,)
    const float* W_out  = (const float*)d_in[9];   // (768,1536)
    float* out = (float*)d_out;                    // (4,2048,768)

    // Workspace carve (floats): ~155.5 MB total
    float* xz   = (float*)d_ws;                               // BL*3072
    float* xc   = xz   + (long)BL * 3072;                     // BL*1536
    float* xdbl = xc   + (long)BL * D_INNER;                  // BL*80
    float* P    = xdbl + (long)BL * 80;                       // 4*32*16*1536
    float* S    = P    + (long)BATCH * NCHUNK * 16 * D_INNER;
    float* H    = S    + (long)BATCH * NCHUNK * 16 * D_INNER;

    // 1) xz = x @ W_in^T   (M=8192, N=3072, K=768)
    {
        dim3 grid(3072 / 128, BL / 128);
        sgemm_nt<0><<<grid, 256, 0, stream>>>(x, W_in, xz, nullptr,
                                              BL, 3072, 768, 768, 768, 3072);
    }
    // 2) depthwise conv + bias + SiLU -> xc
    {
        const long total = (long)BL * D_INNER;
        conv_silu_kernel<<<(int)(total / 256), 256, 0, stream>>>(xz, conv_w, conv_b, xc);
    }
    // 3) x_dbl = xc @ W_x^T  (M=8192, N=80, K=1536)
    {
        dim3 grid(1, BL / 128);
        sgemm_nt<0><<<grid, 256, 0, stream>>>(xc, W_x, xdbl, nullptr,
                                              BL, 80, 1536, 1536, 1536, 80);
    }
    // 4) dt = softplus(x_dbl[:, :48] @ W_dt^T + b_dt) -> xz cols 0..1535
    {
        dim3 grid(1536 / 128, BL / 128);
        sgemm_nt<1><<<grid, 256, 0, stream>>>(xdbl, W_dt, xz, b_dt,
                                              BL, 1536, 48, 80, 48, 3072);
    }
    // 5) scan phase A
    {
        dim3 grid(D_INNER / 256, NCHUNK, BATCH);
        scan_phaseA<<<grid, 256, 0, stream>>>(xc, xz, xdbl, A_log, P, S);
    }
    // 6) scan phase B
    scan_phaseB<<<(BATCH * D_INNER) / 256, 256, 0, stream>>>(P, S, H);
    // 7) scan phase C
    {
        dim3 grid(D_INNER / 256, NCHUNK, BATCH);
        scan_phaseC<<<grid, 256, 0, stream>>>(xc, xz, xdbl, A_log, D_p, H);
    }
    // 8) out = y @ W_out^T  (M=8192, N=768, K=1536)
    {
        dim3 grid(768 / 128, BL / 128);
        sgemm_nt<0><<<grid, 256, 0, stream>>>(xc, W_out, out, nullptr,
                                              BL, 768, 1536, 1536, 1536, 768);
    }
}

// Round 2
// 911.448 us; speedup vs baseline: 1.5240x; 1.5240x over previous
//
#include <hip/hip_runtime.h>
#include <hip/hip_bf16.h>
#include <math.h>

// Problem constants (fixed by reference)
#define D_MODEL   768
#define D_STATE   16
#define D_CONV    4
#define D_INNER   1536
#define DT_RANK   48
#define BATCH     4
#define SEQ_LEN   2048
#define BL        (BATCH * SEQ_LEN)        // 8192 rows
#define NCHUNK    32
#define CHUNK     (SEQ_LEN / NCHUNK)       // 64

typedef __bf16 bf16x8 __attribute__((ext_vector_type(8)));
typedef float  f32x4  __attribute__((ext_vector_type(4)));

__device__ __forceinline__ void async_copy16(const void* g, void* l) {
    __builtin_amdgcn_global_load_lds(
        (const __attribute__((address_space(1))) void*)g,
        (__attribute__((address_space(3))) void*)l,
        16, 0, 0);
}

// ---------------------------------------------------------------------------
// Split-bf16 MFMA GEMM (NT): C[m,n] = sum_k A[m,k]*B[n,k] in ~fp32 precision.
// A stored as M x 2K bf16  [A_hi | A_lo], B stored as N x 2K bf16 [B_hi | B_lo].
// Logical K' = 3K walked as slices A:{hi,hi,lo} x B:{hi,lo,hi}
//   => C = Ah*Bh + Ah*Bl + Al*Bh   (drops Al*Bl ~ 2^-18)
// 128x128 tile, BK=32, 4 waves of 64x64 (4x4 of 16x16x32 MFMA),
// global_load_lds width-16 staging (m97 structure).
// M, N multiples of 128; K multiple of 32.
// ---------------------------------------------------------------------------
__global__ __launch_bounds__(256)
void gemm_split_nt(const __bf16* __restrict__ A, const __bf16* __restrict__ B,
                   float* __restrict__ C, int M, int N, int K, int ldc)
{
    __shared__ __bf16 Asl[128 * 32];
    __shared__ __bf16 Bsl[128 * 32];

    const int tid  = threadIdx.x;
    const int lane = tid & 63;
    const int w    = tid >> 6;          // wave 0..3
    const int wm   = (w >> 1) * 64;     // wave row offset in tile
    const int wn   = (w & 1) * 64;      // wave col offset in tile

    const int bm = blockIdx.y * 128;
    const int bn = blockIdx.x * 128;

    const long lda = 2L * K;
    const long ldb = 2L * K;

    f32x4 acc[4][4];
    #pragma unroll
    for (int i = 0; i < 4; ++i)
        #pragma unroll
        for (int j = 0; j < 4; ++j)
            acc[i][j] = (f32x4){0.f, 0.f, 0.f, 0.f};

    // staging addresses: wave w loads tile rows [w*32, w*32+32)
    // instr j covers 16 rows; lane -> row (lane>>2), 16B chunk (lane&3)
    const int srow = w * 32 + (lane >> 2);
    const int kc8  = (lane & 3) * 8;                 // bf16 col offset
    const __bf16* Abase = A + (long)(bm + srow) * lda + kc8;
    const __bf16* Bbase = B + (long)(bn + srow) * ldb + kc8;
    char* AslW = (char*)Asl + (w * 32) * 64;         // 64B per row
    char* BslW = (char*)Bsl + (w * 32) * 64;

    const int K2 = 2 * K;
    const int KT = (3 * K) / 32;
    for (int kt = 0; kt < KT; ++kt) {
        const int kp = kt * 32;
        const int ka = (kp < K)  ? kp : kp - K;      // A slice map: hi,hi,lo
        const int kb = (kp < K2) ? kp : kp - K2;     // B slice map: hi,lo,hi

        __syncthreads();   // all waves done reading previous tile
        async_copy16(Abase + ka,            AslW);
        async_copy16(Abase + 16 * lda + ka, AslW + 16 * 64);
        async_copy16(Bbase + kb,            BslW);
        async_copy16(Bbase + 16 * ldb + kb, BslW + 16 * 64);
        __syncthreads();   // compiler drains vmcnt before barrier -> data ready

        bf16x8 af[4], bfr[4];
        #pragma unroll
        for (int t = 0; t < 4; ++t) {
            af[t]  = *(const bf16x8*)&Asl[(wm + t * 16 + (lane & 15)) * 32 + (lane >> 4) * 8];
            bfr[t] = *(const bf16x8*)&Bsl[(wn + t * 16 + (lane & 15)) * 32 + (lane >> 4) * 8];
        }
        #pragma unroll
        for (int i = 0; i < 4; ++i)
            #pragma unroll
            for (int j = 0; j < 4; ++j)
                acc[i][j] = __builtin_amdgcn_mfma_f32_16x16x32_bf16(af[i], bfr[j], acc[i][j], 0, 0, 0);
    }

    // C/D layout (m89-verified): col = lane&15, row = (lane>>4)*4 + reg
    const int cn  = lane & 15;
    const int cr4 = (lane >> 4) * 4;
    #pragma unroll
    for (int i = 0; i < 4; ++i)
        #pragma unroll
        for (int j = 0; j < 4; ++j)
            #pragma unroll
            for (int r = 0; r < 4; ++r) {
                const int row = bm + wm + i * 16 + cr4 + r;
                const int col = bn + wn + j * 16 + cn;
                C[(long)row * ldc + col] = acc[i][j][r];
            }
}

// ---------------------------------------------------------------------------
// fp32 -> split-bf16 [hi|lo] rows.  src: rows x K fp32, dst: rows x 2K bf16.
// ---------------------------------------------------------------------------
__global__ __launch_bounds__(256)
void split_bf16_kernel(const float* __restrict__ src, __bf16* __restrict__ dst,
                       int K, long n)
{
    const long i = (long)blockIdx.x * 256 + threadIdx.x;
    if (i >= n) return;
    const long row = i / K;
    const int  col = (int)(i - row * K);
    const float a = src[i];
    const __bf16 h = (__bf16)a;
    const __bf16 l = (__bf16)(a - (float)h);
    __bf16* d = dst + row * (2L * K) + col;
    d[0] = h;
    d[K] = l;
}

// ---------------------------------------------------------------------------
// Tiled fp32 SGEMM (NT) — kept for the small GEMMs (x_dbl, dt).
// MODE 0: plain store.  MODE 1: softplus(v + bias[n]).
// ---------------------------------------------------------------------------
template <int MODE>
__global__ __launch_bounds__(256)
void sgemm_nt(const float* __restrict__ A, const float* __restrict__ B,
              float* __restrict__ C, const float* __restrict__ bias,
              int M, int N, int K, int lda, int ldb, int ldc)
{
    const int BM = 128, BN = 128, BK = 8;
    __shared__ float As[BK][BM];
    __shared__ float Bs[BK][BN];

    const int tid  = threadIdx.x;
    const int bm   = blockIdx.y * BM;
    const int bn   = blockIdx.x * BN;
    const int lrow = tid >> 1;
    const int lk   = (tid & 1) * 4;

    const float* Aload = A + (long)(bm + lrow) * lda + lk;
    const float* Bload = B + (long)(bn + lrow) * ldb + lk;
    const bool bvalid = (bn + lrow) < N;

    const int tx = tid & 15;
    const int ty = tid >> 4;

    float acc[8][8];
    #pragma unroll
    for (int i = 0; i < 8; ++i)
        #pragma unroll
        for (int j = 0; j < 8; ++j) acc[i][j] = 0.f;

    for (int k0 = 0; k0 < K; k0 += BK) {
        float4 av = *(const float4*)(Aload + k0);
        float4 bv = bvalid ? *(const float4*)(Bload + k0)
                           : make_float4(0.f, 0.f, 0.f, 0.f);
        __syncthreads();
        As[lk + 0][lrow] = av.x; As[lk + 1][lrow] = av.y;
        As[lk + 2][lrow] = av.z; As[lk + 3][lrow] = av.w;
        Bs[lk + 0][lrow] = bv.x; Bs[lk + 1][lrow] = bv.y;
        Bs[lk + 2][lrow] = bv.z; Bs[lk + 3][lrow] = bv.w;
        __syncthreads();

        #pragma unroll
        for (int k = 0; k < BK; ++k) {
            float4 a0 = *(const float4*)&As[k][ty * 8];
            float4 a1 = *(const float4*)&As[k][ty * 8 + 4];
            float4 b0 = *(const float4*)&Bs[k][tx * 8];
            float4 b1 = *(const float4*)&Bs[k][tx * 8 + 4];
            float a[8] = {a0.x, a0.y, a0.z, a0.w, a1.x, a1.y, a1.z, a1.w};
            float b[8] = {b0.x, b0.y, b0.z, b0.w, b1.x, b1.y, b1.z, b1.w};
            #pragma unroll
            for (int i = 0; i < 8; ++i)
                #pragma unroll
                for (int j = 0; j < 8; ++j)
                    acc[i][j] = fmaf(a[i], b[j], acc[i][j]);
        }
    }

    #pragma unroll
    for (int i = 0; i < 8; ++i) {
        const int row = bm + ty * 8 + i;
        #pragma unroll
        for (int j = 0; j < 8; ++j) {
            const int col = bn + tx * 8 + j;
            if (col < N) {
                float v = acc[i][j];
                if (MODE == 1) {
                    v += bias[col];
                    v = fmaxf(v, 0.f) + log1pf(__expf(-fabsf(v)));  // stable softplus
                }
                C[(long)row * ldc + col] = v;
            }
        }
    }
}

// ---------------------------------------------------------------------------
// Depthwise causal conv (width 4) + bias + SiLU.
// ---------------------------------------------------------------------------
__global__ __launch_bounds__(256)
void conv_silu_kernel(const float* __restrict__ xz,
                      const float* __restrict__ conv_w,
                      const float* __restrict__ conv_b,
                      float* __restrict__ xc)
{
    const long idx = (long)blockIdx.x * 256 + threadIdx.x;
    const int d  = (int)(idx % D_INNER);
    const long bl = idx / D_INNER;
    const int l  = (int)(bl % SEQ_LEN);

    const float w0 = conv_w[d * 4 + 0];
    const float w1 = conv_w[d * 4 + 1];
    const float w2 = conv_w[d * 4 + 2];
    const float w3 = conv_w[d * 4 + 3];

    const float* base = xz + bl * 3072 + d;
    float s = conv_b[d];
    if (l >= 3) s = fmaf(base[-3 * 3072], w0, s);
    if (l >= 2) s = fmaf(base[-2 * 3072], w1, s);
    if (l >= 1) s = fmaf(base[-1 * 3072], w2, s);
    s = fmaf(base[0], w3, s);
    const float sig = 1.f / (1.f + __expf(-s));
    xc[bl * D_INNER + d] = s * sig;
}

// ---------------------------------------------------------------------------
// Scan phase A: per (b, d, chunk): P = prod(a_l), S = local scan (h0=0).
// ---------------------------------------------------------------------------
__global__ __launch_bounds__(256)
void scan_phaseA(const float* __restrict__ xc, const float* __restrict__ xz,
                 const float* __restrict__ xdbl, const float* __restrict__ A_log,
                 float* __restrict__ P, float* __restrict__ S)
{
    const int d = blockIdx.x * 256 + threadIdx.x;
    const int c = blockIdx.y;
    const int b = blockIdx.z;

    float An[16], Pr[16], Sr[16];
    #pragma unroll
    for (int n = 0; n < 16; ++n) {
        An[n] = -__expf(A_log[d * 16 + n]);
        Pr[n] = 1.f;
        Sr[n] = 0.f;
    }

    const long bl0 = (long)b * SEQ_LEN + (long)c * CHUNK;
    for (int l = 0; l < CHUNK; ++l) {
        const long bl = bl0 + l;
        const float dt  = xz[bl * 3072 + d];
        const float x   = xc[bl * D_INNER + d];
        const float dtx = dt * x;
        const float* bc = xdbl + bl * 80 + DT_RANK;
        #pragma unroll
        for (int n = 0; n < 16; ++n) {
            const float a = __expf(dt * An[n]);
            Pr[n] *= a;
            Sr[n] = fmaf(a, Sr[n], dtx * bc[n]);
        }
    }

    const long base = ((long)(b * NCHUNK + c) * 16) * D_INNER + d;
    #pragma unroll
    for (int n = 0; n < 16; ++n) {
        P[base + (long)n * D_INNER] = Pr[n];
        S[base + (long)n * D_INNER] = Sr[n];
    }
}

// ---------------------------------------------------------------------------
// Scan phase B: sequential chunk-combine per (b, d): H[c] = h_in for chunk c.
// ---------------------------------------------------------------------------
__global__ __launch_bounds__(256)
void scan_phaseB(const float* __restrict__ P, const float* __restrict__ S,
                 float* __restrict__ H)
{
    const int t = blockIdx.x * 256 + threadIdx.x;
    const int d = t % D_INNER;
    const int b = t / D_INNER;

    float h[16];
    #pragma unroll
    for (int n = 0; n < 16; ++n) h[n] = 0.f;

    for (int c = 0; c < NCHUNK; ++c) {
        const long base = ((long)(b * NCHUNK + c) * 16) * D_INNER + d;
        #pragma unroll
        for (int n = 0; n < 16; ++n) {
            const long i = base + (long)n * D_INNER;
            H[i] = h[n];
            h[n] = fmaf(P[i], h[n], S[i]);
        }
    }
}

// ---------------------------------------------------------------------------
// Scan phase C: re-run chunks from correct h_in, emit y, gate with silu(z),
// write y as split-bf16 [hi|lo] rows (row stride 3072) for the MFMA out-GEMM.
// ---------------------------------------------------------------------------
__global__ __launch_bounds__(256)
void scan_phaseC(const float* __restrict__ xc, const float* __restrict__ xz,
                 const float* __restrict__ xdbl, const float* __restrict__ A_log,
                 const float* __restrict__ Dp, const float* __restrict__ H,
                 __bf16* __restrict__ yS)
{
    const int d = blockIdx.x * 256 + threadIdx.x;
    const int c = blockIdx.y;
    const int b = blockIdx.z;

    float An[16], h[16];
    const long hbase = ((long)(b * NCHUNK + c) * 16) * D_INNER + d;
    #pragma unroll
    for (int n = 0; n < 16; ++n) {
        An[n] = -__expf(A_log[d * 16 + n]);
        h[n]  = H[hbase + (long)n * D_INNER];
    }
    const float Dd = Dp[d];

    const long bl0 = (long)b * SEQ_LEN + (long)c * CHUNK;
    for (int l = 0; l < CHUNK; ++l) {
        const long bl = bl0 + l;
        const float dt  = xz[bl * 3072 + d];
        const float x   = xc[bl * D_INNER + d];
        const float dtx = dt * x;
        const float* bc = xdbl + bl * 80 + DT_RANK;
        float y = Dd * x;
        #pragma unroll
        for (int n = 0; n < 16; ++n) {
            const float a = __expf(dt * An[n]);
            h[n] = fmaf(a, h[n], dtx * bc[n]);
            y = fmaf(h[n], bc[16 + n], y);
        }
        const float z  = xz[bl * 3072 + D_INNER + d];
        const float sz = z / (1.f + __expf(-z));
        const float v  = y * sz;
        const __bf16 hi = (__bf16)v;
        const __bf16 lo = (__bf16)(v - (float)hi);
        yS[bl * 3072 + d]        = hi;
        yS[bl * 3072 + 1536 + d] = lo;
    }
}

// ---------------------------------------------------------------------------
extern "C" void kernel_launch(void* const* d_in, const int* in_sizes, int n_in,
                              void* d_out, int out_size, void* d_ws, size_t ws_size,
                              hipStream_t stream)
{
    const float* x      = (const float*)d_in[0];   // (4,2048,768)
    const float* W_in   = (const float*)d_in[1];   // (3072,768)
    const float* conv_w = (const float*)d_in[2];   // (1536,1,4)
    const float* conv_b = (const float*)d_in[3];   // (1536,)
    const float* W_x    = (const float*)d_in[4];   // (80,1536)
    const float* W_dt   = (const float*)d_in[5];   // (1536,48)
    const float* b_dt   = (const float*)d_in[6];   // (1536,)
    const float* A_log  = (const float*)d_in[7];   // (1536,16)
    const float* D_p    = (const float*)d_in[8];   // (1536,)
    const float* W_out  = (const float*)d_in[9];   // (768,1536)
    float* out = (float*)d_out;                    // (4,2048,768)

    // ---- workspace carve (with region overlays) -------------------------
    char* p = (char*)d_ws;
    auto take = [&](size_t bytes) { char* r = p; p += (bytes + 255) & ~(size_t)255; return r; };

    float* xz   = (float*)take((size_t)BL * 3072 * 4);   // 100.7 MB (xb->dt | z)
    float* xc   = (float*)take((size_t)BL * 1536 * 4);   //  50.3 MB
    float* xdbl = (float*)take((size_t)BL * 80 * 4);     //   2.6 MB
    float* H    = (float*)take((size_t)BATCH * NCHUNK * 16 * D_INNER * 4);  // 12.6 MB
    __bf16* wOutS = (__bf16*)take(768L * 3072 * 2);      //   4.7 MB

    // REGION (50.4 MB), time-multiplexed:
    //   phase 1-2: xS (8192x1536 bf16 = 25.2MB) + wInS (3072x1536 bf16 = 9.4MB)
    //   phase 6-7: P (12.6MB) + S (12.6MB)
    //   phase 8-9: yS (8192x3072 bf16 = 50.3MB)
    char* region = take(50331648);
    __bf16* xS   = (__bf16*)region;
    __bf16* wInS = (__bf16*)(region + 25165824);
    float*  P    = (float*)region;
    float*  S    = (float*)(region + 12582912);
    __bf16* yS   = (__bf16*)region;

    // 0) split conversions for in-proj
    {
        const long nx = (long)BL * 768;
        split_bf16_kernel<<<(int)((nx + 255) / 256), 256, 0, stream>>>(x, xS, 768, nx);
        const long nw = 3072L * 768;
        split_bf16_kernel<<<(int)((nw + 255) / 256), 256, 0, stream>>>(W_in, wInS, 768, nw);
        const long no = 768L * 1536;
        split_bf16_kernel<<<(int)((no + 255) / 256), 256, 0, stream>>>(W_out, wOutS, 1536, no);
    }
    // 1) xz = x @ W_in^T via split-bf16 MFMA (M=8192, N=3072, K=768)
    {
        dim3 grid(3072 / 128, BL / 128);
        gemm_split_nt<<<grid, 256, 0, stream>>>(xS, wInS, xz, BL, 3072, 768, 3072);
    }
    // 2) depthwise conv + bias + SiLU -> xc
    {
        const long total = (long)BL * D_INNER;
        conv_silu_kernel<<<(int)(total / 256), 256, 0, stream>>>(xz, conv_w, conv_b, xc);
    }
    // 3) x_dbl = xc @ W_x^T  (M=8192, N=80, K=1536) — fp32
    {
        dim3 grid(1, BL / 128);
        sgemm_nt<0><<<grid, 256, 0, stream>>>(xc, W_x, xdbl, nullptr,
                                              BL, 80, 1536, 1536, 1536, 80);
    }
    // 4) dt = softplus(x_dbl[:, :48] @ W_dt^T + b_dt) -> xz cols 0..1535 — fp32
    {
        dim3 grid(1536 / 128, BL / 128);
        sgemm_nt<1><<<grid, 256, 0, stream>>>(xdbl, W_dt, xz, b_dt,
                                              BL, 1536, 48, 80, 48, 3072);
    }
    // 5) scan phase A
    {
        dim3 grid(D_INNER / 256, NCHUNK, BATCH);
        scan_phaseA<<<grid, 256, 0, stream>>>(xc, xz, xdbl, A_log, P, S);
    }
    // 6) scan phase B
    scan_phaseB<<<(BATCH * D_INNER) / 256, 256, 0, stream>>>(P, S, H);
    // 7) scan phase C -> yS (split-bf16)   [P,S dead from here; yS overlays them]
    {
        dim3 grid(D_INNER / 256, NCHUNK, BATCH);
        scan_phaseC<<<grid, 256, 0, stream>>>(xc, xz, xdbl, A_log, D_p, H, yS);
    }
    // 8) out = y @ W_out^T via split-bf16 MFMA (M=8192, N=768, K=1536)
    {
        dim3 grid(768 / 128, BL / 128);
        gemm_split_nt<<<grid, 256, 0, stream>>>(yS, wOutS, out, BL, 768, 1536, 768);
    }
}

// Round 3
// 775.433 us; speedup vs baseline: 1.7914x; 1.1754x over previous
//
#include <hip/hip_runtime.h>
#include <hip/hip_bf16.h>
#include <math.h>

// Problem constants (fixed by reference)
#define D_MODEL   768
#define D_STATE   16
#define D_CONV    4
#define D_INNER   1536
#define DT_RANK   48
#define BATCH     4
#define SEQ_LEN   2048
#define BL        (BATCH * SEQ_LEN)        // 8192 rows
#define NCHUNK    32
#define CHUNK     (SEQ_LEN / NCHUNK)       // 64

typedef __bf16 bf16x8 __attribute__((ext_vector_type(8)));
typedef float  f32x4  __attribute__((ext_vector_type(4)));

__device__ __forceinline__ void async_copy16(const void* g, void* l) {
    __builtin_amdgcn_global_load_lds(
        (const __attribute__((address_space(1))) void*)g,
        (__attribute__((address_space(3))) void*)l,
        16, 0, 0);
}

// ---------------------------------------------------------------------------
// Split-bf16 MFMA GEMM (NT): C[m,n] = sum_k A[m,k]*B[n,k] in ~fp32 precision.
// A: M x 2K bf16 [A_hi | A_lo], B: N x 2K bf16 [B_hi | B_lo].
// Logical K' = 3K walked as slices A:{hi,hi,lo} x B:{hi,lo,hi}
//   => C = Ah*Bh + Ah*Bl + Al*Bh   (drops Al*Bl ~ 2^-18)
// 128x128 tile, BK=32, 4 waves of 64x64 (4x4 of 16x16x32 MFMA).
// ---------------------------------------------------------------------------
__global__ __launch_bounds__(256)
void gemm_split_nt(const __bf16* __restrict__ A, const __bf16* __restrict__ B,
                   float* __restrict__ C, int M, int N, int K, int ldc)
{
    __shared__ __bf16 Asl[128 * 32];
    __shared__ __bf16 Bsl[128 * 32];

    const int tid  = threadIdx.x;
    const int lane = tid & 63;
    const int w    = tid >> 6;
    const int wm   = (w >> 1) * 64;
    const int wn   = (w & 1) * 64;

    const int bm = blockIdx.y * 128;
    const int bn = blockIdx.x * 128;

    const long lda = 2L * K;
    const long ldb = 2L * K;

    f32x4 acc[4][4];
    #pragma unroll
    for (int i = 0; i < 4; ++i)
        #pragma unroll
        for (int j = 0; j < 4; ++j)
            acc[i][j] = (f32x4){0.f, 0.f, 0.f, 0.f};

    const int srow = w * 32 + (lane >> 2);
    const int kc8  = (lane & 3) * 8;
    const __bf16* Abase = A + (long)(bm + srow) * lda + kc8;
    const __bf16* Bbase = B + (long)(bn + srow) * ldb + kc8;
    char* AslW = (char*)Asl + (w * 32) * 64;
    char* BslW = (char*)Bsl + (w * 32) * 64;

    const int K2 = 2 * K;
    const int KT = (3 * K) / 32;
    for (int kt = 0; kt < KT; ++kt) {
        const int kp = kt * 32;
        const int ka = (kp < K)  ? kp : kp - K;      // A slices: hi,hi,lo
        const int kb = (kp < K2) ? kp : kp - K2;     // B slices: hi,lo,hi

        __syncthreads();
        async_copy16(Abase + ka,            AslW);
        async_copy16(Abase + 16 * lda + ka, AslW + 16 * 64);
        async_copy16(Bbase + kb,            BslW);
        async_copy16(Bbase + 16 * ldb + kb, BslW + 16 * 64);
        __syncthreads();

        bf16x8 af[4], bfr[4];
        #pragma unroll
        for (int t = 0; t < 4; ++t) {
            af[t]  = *(const bf16x8*)&Asl[(wm + t * 16 + (lane & 15)) * 32 + (lane >> 4) * 8];
            bfr[t] = *(const bf16x8*)&Bsl[(wn + t * 16 + (lane & 15)) * 32 + (lane >> 4) * 8];
        }
        #pragma unroll
        for (int i = 0; i < 4; ++i)
            #pragma unroll
            for (int j = 0; j < 4; ++j)
                acc[i][j] = __builtin_amdgcn_mfma_f32_16x16x32_bf16(af[i], bfr[j], acc[i][j], 0, 0, 0);
    }

    const int cn  = lane & 15;
    const int cr4 = (lane >> 4) * 4;
    #pragma unroll
    for (int i = 0; i < 4; ++i)
        #pragma unroll
        for (int j = 0; j < 4; ++j)
            #pragma unroll
            for (int r = 0; r < 4; ++r) {
                const int row = bm + wm + i * 16 + cr4 + r;
                const int col = bn + wn + j * 16 + cn;
                C[(long)row * ldc + col] = acc[i][j][r];
            }
}

// ---------------------------------------------------------------------------
// x_dbl split-K MFMA GEMM: A = xcS (8192 x 3072 bf16 split), B = W_xS
// (128-row padded panel, 80 valid), K=1536, K'=4608 -> 144 k-tiles split 4.
// grid(4, 64); partials to Pout[s][8192][128].
// Pad cols 80..127 of C are garbage (pad B rows unread elsewhere) — never read.
// ---------------------------------------------------------------------------
__global__ __launch_bounds__(256)
void gemm_xdbl(const __bf16* __restrict__ A, const __bf16* __restrict__ B,
               float* __restrict__ Pout)
{
    __shared__ __bf16 Asl[128 * 32];
    __shared__ __bf16 Bsl[128 * 32];

    const int tid  = threadIdx.x;
    const int lane = tid & 63;
    const int w    = tid >> 6;
    const int wm   = (w >> 1) * 64;
    const int wn   = (w & 1) * 64;

    const int s  = blockIdx.x;           // split-K index 0..3
    const int bm = blockIdx.y * 128;
    const long lda = 3072, ldb = 3072;
    const int K = 1536, K2 = 3072;

    f32x4 acc[4][4];
    #pragma unroll
    for (int i = 0; i < 4; ++i)
        #pragma unroll
        for (int j = 0; j < 4; ++j)
            acc[i][j] = (f32x4){0.f, 0.f, 0.f, 0.f};

    const int srow = w * 32 + (lane >> 2);
    const int kc8  = (lane & 3) * 8;
    const __bf16* Abase = A + (long)(bm + srow) * lda + kc8;
    const __bf16* Bbase = B + (long)srow * ldb + kc8;
    char* AslW = (char*)Asl + (w * 32) * 64;
    char* BslW = (char*)Bsl + (w * 32) * 64;

    for (int kt = s * 36; kt < (s + 1) * 36; ++kt) {
        const int kp = kt * 32;
        const int ka = (kp < K)  ? kp : kp - K;
        const int kb = (kp < K2) ? kp : kp - K2;

        __syncthreads();
        async_copy16(Abase + ka,            AslW);
        async_copy16(Abase + 16 * lda + ka, AslW + 16 * 64);
        async_copy16(Bbase + kb,            BslW);
        async_copy16(Bbase + 16 * ldb + kb, BslW + 16 * 64);
        __syncthreads();

        bf16x8 af[4], bfr[4];
        #pragma unroll
        for (int t = 0; t < 4; ++t) {
            af[t]  = *(const bf16x8*)&Asl[(wm + t * 16 + (lane & 15)) * 32 + (lane >> 4) * 8];
            bfr[t] = *(const bf16x8*)&Bsl[(wn + t * 16 + (lane & 15)) * 32 + (lane >> 4) * 8];
        }
        #pragma unroll
        for (int i = 0; i < 4; ++i)
            #pragma unroll
            for (int j = 0; j < 4; ++j)
                acc[i][j] = __builtin_amdgcn_mfma_f32_16x16x32_bf16(af[i], bfr[j], acc[i][j], 0, 0, 0);
    }

    float* Cp = Pout + (long)s * (8192L * 128);
    const int cn  = lane & 15;
    const int cr4 = (lane >> 4) * 4;
    #pragma unroll
    for (int i = 0; i < 4; ++i)
        #pragma unroll
        for (int j = 0; j < 4; ++j)
            #pragma unroll
            for (int r = 0; r < 4; ++r) {
                const int row = bm + wm + i * 16 + cr4 + r;
                const int col = wn + j * 16 + cn;
                Cp[(long)row * 128 + col] = acc[i][j][r];
            }
}

// Reduce 4 split-K partials (ld 128) into xdbl (ld 80).
__global__ __launch_bounds__(256)
void xdbl_reduce(const float* __restrict__ Pout, float* __restrict__ xdbl)
{
    const long i = (long)blockIdx.x * 256 + threadIdx.x;   // over 8192*80
    if (i >= 8192L * 80) return;
    const long r = i / 80;
    const int  c = (int)(i - r * 80);
    const long o = r * 128 + c;
    const long st = 8192L * 128;
    xdbl[i] = (Pout[o] + Pout[o + st]) + (Pout[o + 2 * st] + Pout[o + 3 * st]);
}

// ---------------------------------------------------------------------------
// fp32 -> split-bf16 [hi|lo] rows.  src: rows x K fp32, dst: rows x 2K bf16.
// ---------------------------------------------------------------------------
__global__ __launch_bounds__(256)
void split_bf16_kernel(const float* __restrict__ src, __bf16* __restrict__ dst,
                       int K, long n)
{
    const long i = (long)blockIdx.x * 256 + threadIdx.x;
    if (i >= n) return;
    const long row = i / K;
    const int  col = (int)(i - row * K);
    const float a = src[i];
    const __bf16 h = (__bf16)a;
    const __bf16 l = (__bf16)(a - (float)h);
    __bf16* d = dst + row * (2L * K) + col;
    d[0] = h;
    d[K] = l;
}

// ---------------------------------------------------------------------------
// Tiled fp32 SGEMM (NT) — kept for the dt GEMM (K=48).
// MODE 1: softplus(v + bias[n]).
// ---------------------------------------------------------------------------
template <int MODE>
__global__ __launch_bounds__(256)
void sgemm_nt(const float* __restrict__ A, const float* __restrict__ B,
              float* __restrict__ C, const float* __restrict__ bias,
              int M, int N, int K, int lda, int ldb, int ldc)
{
    const int BM = 128, BN = 128, BK = 8;
    __shared__ float As[BK][BM];
    __shared__ float Bs[BK][BN];

    const int tid  = threadIdx.x;
    const int bm   = blockIdx.y * BM;
    const int bn   = blockIdx.x * BN;
    const int lrow = tid >> 1;
    const int lk   = (tid & 1) * 4;

    const float* Aload = A + (long)(bm + lrow) * lda + lk;
    const float* Bload = B + (long)(bn + lrow) * ldb + lk;
    const bool bvalid = (bn + lrow) < N;

    const int tx = tid & 15;
    const int ty = tid >> 4;

    float acc[8][8];
    #pragma unroll
    for (int i = 0; i < 8; ++i)
        #pragma unroll
        for (int j = 0; j < 8; ++j) acc[i][j] = 0.f;

    for (int k0 = 0; k0 < K; k0 += BK) {
        float4 av = *(const float4*)(Aload + k0);
        float4 bv = bvalid ? *(const float4*)(Bload + k0)
                           : make_float4(0.f, 0.f, 0.f, 0.f);
        __syncthreads();
        As[lk + 0][lrow] = av.x; As[lk + 1][lrow] = av.y;
        As[lk + 2][lrow] = av.z; As[lk + 3][lrow] = av.w;
        Bs[lk + 0][lrow] = bv.x; Bs[lk + 1][lrow] = bv.y;
        Bs[lk + 2][lrow] = bv.z; Bs[lk + 3][lrow] = bv.w;
        __syncthreads();

        #pragma unroll
        for (int k = 0; k < BK; ++k) {
            float4 a0 = *(const float4*)&As[k][ty * 8];
            float4 a1 = *(const float4*)&As[k][ty * 8 + 4];
            float4 b0 = *(const float4*)&Bs[k][tx * 8];
            float4 b1 = *(const float4*)&Bs[k][tx * 8 + 4];
            float a[8] = {a0.x, a0.y, a0.z, a0.w, a1.x, a1.y, a1.z, a1.w};
            float b[8] = {b0.x, b0.y, b0.z, b0.w, b1.x, b1.y, b1.z, b1.w};
            #pragma unroll
            for (int i = 0; i < 8; ++i)
                #pragma unroll
                for (int j = 0; j < 8; ++j)
                    acc[i][j] = fmaf(a[i], b[j], acc[i][j]);
        }
    }

    #pragma unroll
    for (int i = 0; i < 8; ++i) {
        const int row = bm + ty * 8 + i;
        #pragma unroll
        for (int j = 0; j < 8; ++j) {
            const int col = bn + tx * 8 + j;
            if (col < N) {
                float v = acc[i][j];
                if (MODE == 1) {
                    v += bias[col];
                    v = fmaxf(v, 0.f) + log1pf(__expf(-fabsf(v)));  // stable softplus
                }
                C[(long)row * ldc + col] = v;
            }
        }
    }
}

// ---------------------------------------------------------------------------
// Depthwise causal conv (width 4) + bias + SiLU -> xc fp32 AND xcS split-bf16.
// ---------------------------------------------------------------------------
__global__ __launch_bounds__(256)
void conv_silu_kernel(const float* __restrict__ xz,
                      const float* __restrict__ conv_w,
                      const float* __restrict__ conv_b,
                      float* __restrict__ xc,
                      __bf16* __restrict__ xcS)
{
    const long idx = (long)blockIdx.x * 256 + threadIdx.x;
    const int d  = (int)(idx % D_INNER);
    const long bl = idx / D_INNER;
    const int l  = (int)(bl % SEQ_LEN);

    const float w0 = conv_w[d * 4 + 0];
    const float w1 = conv_w[d * 4 + 1];
    const float w2 = conv_w[d * 4 + 2];
    const float w3 = conv_w[d * 4 + 3];

    const float* base = xz + bl * 3072 + d;
    float s = conv_b[d];
    if (l >= 3) s = fmaf(base[-3 * 3072], w0, s);
    if (l >= 2) s = fmaf(base[-2 * 3072], w1, s);
    if (l >= 1) s = fmaf(base[-1 * 3072], w2, s);
    s = fmaf(base[0], w3, s);
    const float sig = 1.f / (1.f + __expf(-s));
    const float v = s * sig;
    xc[bl * D_INNER + d] = v;
    const __bf16 hi = (__bf16)v;
    const __bf16 lo = (__bf16)(v - (float)hi);
    xcS[bl * 3072 + d]        = hi;
    xcS[bl * 3072 + 1536 + d] = lo;
}

// ---------------------------------------------------------------------------
// Scan phase A: per (b, d, chunk): P = prod(a_l), S = local scan (h0=0).
// ---------------------------------------------------------------------------
__global__ __launch_bounds__(256)
void scan_phaseA(const float* __restrict__ xc, const float* __restrict__ xz,
                 const float* __restrict__ xdbl, const float* __restrict__ A_log,
                 float* __restrict__ P, float* __restrict__ S)
{
    const int d = blockIdx.x * 256 + threadIdx.x;
    const int c = blockIdx.y;
    const int b = blockIdx.z;

    float An[16], Pr[16], Sr[16];
    #pragma unroll
    for (int n = 0; n < 16; ++n) {
        An[n] = -__expf(A_log[d * 16 + n]);
        Pr[n] = 1.f;
        Sr[n] = 0.f;
    }

    const long bl0 = (long)b * SEQ_LEN + (long)c * CHUNK;
    for (int l = 0; l < CHUNK; ++l) {
        const long bl = bl0 + l;
        const float dt  = xz[bl * 3072 + d];
        const float x   = xc[bl * D_INNER + d];
        const float dtx = dt * x;
        const float* bc = xdbl + bl * 80 + DT_RANK;
        #pragma unroll
        for (int n = 0; n < 16; ++n) {
            const float a = __expf(dt * An[n]);
            Pr[n] *= a;
            Sr[n] = fmaf(a, Sr[n], dtx * bc[n]);
        }
    }

    const long base = ((long)(b * NCHUNK + c) * 16) * D_INNER + d;
    #pragma unroll
    for (int n = 0; n < 16; ++n) {
        P[base + (long)n * D_INNER] = Pr[n];
        S[base + (long)n * D_INNER] = Sr[n];
    }
}

// ---------------------------------------------------------------------------
// Scan phase B: sequential chunk-combine per (b, d): H[c] = h_in for chunk c.
// ---------------------------------------------------------------------------
__global__ __launch_bounds__(256)
void scan_phaseB(const float* __restrict__ P, const float* __restrict__ S,
                 float* __restrict__ H)
{
    const int t = blockIdx.x * 256 + threadIdx.x;
    const int d = t % D_INNER;
    const int b = t / D_INNER;

    float h[16];
    #pragma unroll
    for (int n = 0; n < 16; ++n) h[n] = 0.f;

    for (int c = 0; c < NCHUNK; ++c) {
        const long base = ((long)(b * NCHUNK + c) * 16) * D_INNER + d;
        #pragma unroll
        for (int n = 0; n < 16; ++n) {
            const long i = base + (long)n * D_INNER;
            H[i] = h[n];
            h[n] = fmaf(P[i], h[n], S[i]);
        }
    }
}

// ---------------------------------------------------------------------------
// Scan phase C: re-run chunks from correct h_in, emit y, gate with silu(z),
// write y as split-bf16 [hi|lo] rows (row stride 3072) for the MFMA out-GEMM.
// ---------------------------------------------------------------------------
__global__ __launch_bounds__(256)
void scan_phaseC(const float* __restrict__ xc, const float* __restrict__ xz,
                 const float* __restrict__ xdbl, const float* __restrict__ A_log,
                 const float* __restrict__ Dp, const float* __restrict__ H,
                 __bf16* __restrict__ yS)
{
    const int d = blockIdx.x * 256 + threadIdx.x;
    const int c = blockIdx.y;
    const int b = blockIdx.z;

    float An[16], h[16];
    const long hbase = ((long)(b * NCHUNK + c) * 16) * D_INNER + d;
    #pragma unroll
    for (int n = 0; n < 16; ++n) {
        An[n] = -__expf(A_log[d * 16 + n]);
        h[n]  = H[hbase + (long)n * D_INNER];
    }
    const float Dd = Dp[d];

    const long bl0 = (long)b * SEQ_LEN + (long)c * CHUNK;
    for (int l = 0; l < CHUNK; ++l) {
        const long bl = bl0 + l;
        const float dt  = xz[bl * 3072 + d];
        const float x   = xc[bl * D_INNER + d];
        const float dtx = dt * x;
        const float* bc = xdbl + bl * 80 + DT_RANK;
        float y = Dd * x;
        #pragma unroll
        for (int n = 0; n < 16; ++n) {
            const float a = __expf(dt * An[n]);
            h[n] = fmaf(a, h[n], dtx * bc[n]);
            y = fmaf(h[n], bc[16 + n], y);
        }
        const float z  = xz[bl * 3072 + D_INNER + d];
        const float sz = z / (1.f + __expf(-z));
        const float v  = y * sz;
        const __bf16 hi = (__bf16)v;
        const __bf16 lo = (__bf16)(v - (float)hi);
        yS[bl * 3072 + d]        = hi;
        yS[bl * 3072 + 1536 + d] = lo;
    }
}

// ---------------------------------------------------------------------------
extern "C" void kernel_launch(void* const* d_in, const int* in_sizes, int n_in,
                              void* d_out, int out_size, void* d_ws, size_t ws_size,
                              hipStream_t stream)
{
    const float* x      = (const float*)d_in[0];   // (4,2048,768)
    const float* W_in   = (const float*)d_in[1];   // (3072,768)
    const float* conv_w = (const float*)d_in[2];   // (1536,1,4)
    const float* conv_b = (const float*)d_in[3];   // (1536,)
    const float* W_x    = (const float*)d_in[4];   // (80,1536)
    const float* W_dt   = (const float*)d_in[5];   // (1536,48)
    const float* b_dt   = (const float*)d_in[6];   // (1536,)
    const float* A_log  = (const float*)d_in[7];   // (1536,16)
    const float* D_p    = (const float*)d_in[8];   // (1536,)
    const float* W_out  = (const float*)d_in[9];   // (768,1536)
    float* out = (float*)d_out;                    // (4,2048,768)

    // ---- workspace carve (with region overlays), ~239 MB ----------------
    char* p = (char*)d_ws;
    auto take = [&](size_t bytes) { char* r = p; p += (bytes + 255) & ~(size_t)255; return r; };

    float*  xz    = (float*)take((size_t)BL * 3072 * 4);    // 100.7 MB (dt | z)
    float*  xc    = (float*)take((size_t)BL * 1536 * 4);    //  50.3 MB
    float*  xdbl  = (float*)take((size_t)BL * 80 * 4);      //   2.6 MB
    float*  H     = (float*)take((size_t)BATCH * NCHUNK * 16 * D_INNER * 4); // 12.6 MB
    __bf16* wOutS = (__bf16*)take(768L * 3072 * 2);         //   4.7 MB
    __bf16* wXS   = (__bf16*)take(128L * 3072 * 2);         //   0.8 MB (80 valid rows)
    float*  Pout  = (float*)take(4L * 8192 * 128 * 4);      //  16.8 MB split-K partials

    // REGION (50.4 MB), time-multiplexed:
    //   phase 1:   xS (25.2MB) + wInS (9.4MB)
    //   phase 2-3: xcS (8192x3072 bf16 = 50.3MB)
    //   phase 6-7: P (12.6MB) + S (12.6MB)
    //   phase 8-9: yS (50.3MB)
    char* region = take(50331648);
    __bf16* xS   = (__bf16*)region;
    __bf16* wInS = (__bf16*)(region + 25165824);
    __bf16* xcS  = (__bf16*)region;
    float*  P    = (float*)region;
    float*  S    = (float*)(region + 12582912);
    __bf16* yS   = (__bf16*)region;

    // 0) split conversions
    {
        const long nx = (long)BL * 768;
        split_bf16_kernel<<<(int)((nx + 255) / 256), 256, 0, stream>>>(x, xS, 768, nx);
        const long nw = 3072L * 768;
        split_bf16_kernel<<<(int)((nw + 255) / 256), 256, 0, stream>>>(W_in, wInS, 768, nw);
        const long no = 768L * 1536;
        split_bf16_kernel<<<(int)((no + 255) / 256), 256, 0, stream>>>(W_out, wOutS, 1536, no);
        const long nxw = 80L * 1536;
        split_bf16_kernel<<<(int)((nxw + 255) / 256), 256, 0, stream>>>(W_x, wXS, 1536, nxw);
    }
    // 1) xz = x @ W_in^T via split-bf16 MFMA (M=8192, N=3072, K=768)
    {
        dim3 grid(3072 / 128, BL / 128);
        gemm_split_nt<<<grid, 256, 0, stream>>>(xS, wInS, xz, BL, 3072, 768, 3072);
    }
    // 2) depthwise conv + bias + SiLU -> xc (fp32) + xcS (split-bf16; overlays xS)
    {
        const long total = (long)BL * D_INNER;
        conv_silu_kernel<<<(int)(total / 256), 256, 0, stream>>>(xz, conv_w, conv_b, xc, xcS);
    }
    // 3) x_dbl split-K MFMA: Pout[s] = xcS @ wXS^T chunks  (grid 4x64)
    {
        dim3 grid(4, BL / 128);
        gemm_xdbl<<<grid, 256, 0, stream>>>(xcS, wXS, Pout);
    }
    // 4) reduce partials -> xdbl (ld 80)
    {
        const long n = 8192L * 80;
        xdbl_reduce<<<(int)((n + 255) / 256), 256, 0, stream>>>(Pout, xdbl);
    }
    // 5) dt = softplus(x_dbl[:, :48] @ W_dt^T + b_dt) -> xz cols 0..1535 (fp32)
    {
        dim3 grid(1536 / 128, BL / 128);
        sgemm_nt<1><<<grid, 256, 0, stream>>>(xdbl, W_dt, xz, b_dt,
                                              BL, 1536, 48, 80, 48, 3072);
    }
    // 6) scan phase A  (P,S overlay region; xcS dead after phase 3)
    {
        dim3 grid(D_INNER / 256, NCHUNK, BATCH);
        scan_phaseA<<<grid, 256, 0, stream>>>(xc, xz, xdbl, A_log, P, S);
    }
    // 7) scan phase B
    scan_phaseB<<<(BATCH * D_INNER) / 256, 256, 0, stream>>>(P, S, H);
    // 8) scan phase C -> yS (split-bf16; P,S dead)
    {
        dim3 grid(D_INNER / 256, NCHUNK, BATCH);
        scan_phaseC<<<grid, 256, 0, stream>>>(xc, xz, xdbl, A_log, D_p, H, yS);
    }
    // 9) out = y @ W_out^T via split-bf16 MFMA (M=8192, N=768, K=1536)
    {
        dim3 grid(768 / 128, BL / 128);
        gemm_split_nt<<<grid, 256, 0, stream>>>(yS, wOutS, out, BL, 768, 1536, 768);
    }
}